// Round 9
// baseline (255.344 us; speedup 1.0000x reference)
//
#include <hip/hip_runtime.h>

typedef __attribute__((ext_vector_type(8))) short short8;
typedef __attribute__((ext_vector_type(4))) float f32x4;
typedef __attribute__((ext_vector_type(4))) unsigned short u16x4;

__device__ __forceinline__ unsigned short f2b(float f) {
  unsigned int u = __float_as_uint(f);
  u += 0x7fffu + ((u >> 16) & 1u);   // RNE
  return (unsigned short)(u >> 16);
}
__device__ __forceinline__ void glds16(const void* g, void* l) {
  __builtin_amdgcn_global_load_lds(
      (const __attribute__((address_space(1))) unsigned int*)g,
      (__attribute__((address_space(3))) unsigned int*)l, 16, 0, 0);
}

// ------------------------------------------------- fused cast: all 5 inputs -> bf16
__global__ __launch_bounds__(256) void cast_all(const float* __restrict__ x,
                                                const float* __restrict__ wq,
                                                const float* __restrict__ wk,
                                                const float* __restrict__ wv,
                                                const float* __restrict__ wo,
                                                unsigned short* __restrict__ dst) {
  const int i = blockIdx.x * 256 + threadIdx.x;   // < 4,718,592 (grid exact)
  const float* s;
  int off;
  if (i < 2097152)      { s = x;  off = i; }
  else if (i < 3145728) { s = wq; off = i - 2097152; }
  else if (i < 3407872) { s = wk; off = i - 3145728; }
  else if (i < 3670016) { s = wv; off = i - 3407872; }
  else                  { s = wo; off = i - 3670016; }
  f32x4 v = ((const f32x4*)s)[off];
  u16x4 o;
  o[0] = f2b(v[0]); o[1] = f2b(v[1]); o[2] = f2b(v[2]); o[3] = f2b(v[3]);
  ((u16x4*)dst)[i] = o;
}

#define BARF()                            \
  asm volatile("" ::: "memory");          \
  __builtin_amdgcn_s_barrier();           \
  asm volatile("" ::: "memory");

// ------------------------------------------------------------------ 128x128 2-phase GEMM
// CO-RESIDENT: BM=BN=128, BK=64 (K=2048, 32 tiles), 8 waves (2Mx4N), 64 KiB LDS ->
// 2 blocks/CU (cross-block overlap hides barrier/vmcnt stalls). VGPR 56 (R7-measured).
// LDS: [16] subtiles of 16x32 bf16 (1024 B) per operand; st_16x32 XOR swizzle via
// pre-swizzled global src. Phases per K-tile:
//   P1: rd af-hi | fence | rd af-lo,bf | stage B(T+1)->c^1 | BAR | MFMA mi-lo | BAR
//   P2: stage A(T+2)->c                | BAR | MFMA mi-hi | vmcnt(2) | BAR
// Soundness / gate induction / tail clamp: see R7 comments (unchanged, measured-good).
// mode=1 (qkv): cb={wn, wn+4} puts rope partners (d,d+64) in acc[mi][0]/[1] ->
// thread-local RoPE; y: 0-15 Q, 16-19 K, 20-23 V(transposed). Grid (32,24).
// mode=0 (wo): plain fp32 C, cb={2wn,2wn+1}; grid (32,16) = 512 blocks = 2/CU
// (replaces the 96KiB-LDS 1-resident gemm128 — same co-residency cure as qkv).
__global__ __launch_bounds__(512, 4) void gemm_t128(
    const unsigned short* __restrict__ A, const unsigned short* __restrict__ B,
    const int mode,
    unsigned short* __restrict__ qb, unsigned short* __restrict__ kb,
    unsigned short* __restrict__ vtg, float* __restrict__ Cout) {
  extern __shared__ char smem[];   // 2 dbuf x [A 16K | B 16K] = 65536 B
  const int tid = threadIdx.x;
  const int w = tid >> 6, lane = tid & 63;
  const int quad = lane >> 4, l15 = lane & 15;
  const int wm = w >> 2, wn = w & 3;
  const int m0 = blockIdx.x * 128;
  const int y  = blockIdx.y;
  const int n0 = y * 128;

  int cb[2];
  cb[0] = mode ? wn : wn * 2;
  cb[1] = mode ? wn + 4 : wn * 2 + 1;

  const int fragOff = l15 * 64 + ((quad * 16) ^ ((l15 & 8) << 2));
  const int sr = lane >> 2;
  const int sc = ((lane & 3) * 8) ^ ((lane & 32) ? 16 : 0);   // bf16 col, pre-swizzled
  const unsigned short* const Abase = A + (size_t)(m0 + (w >> 1) * 16 + sr) * 2048 + (w & 1) * 32 + sc;
  const unsigned short* const Bbase = B + (size_t)(n0 + (w >> 1) * 16 + sr) * 2048 + (w & 1) * 32 + sc;

#define T_STAGE_A(tt)                                                                    \
  {                                                                                      \
    const int t_ = ((tt) < 32) ? (tt) : 31;                                              \
    char* const d_ = smem + (t_ & 1) * 32768 + w * 1024;                                 \
    glds16(Abase + (size_t)t_ * 64, d_);                                                 \
    glds16(Abase + (64 * 2048) + (size_t)t_ * 64, d_ + 8192);                            \
  }
#define T_STAGE_B(tt)                                                                    \
  {                                                                                      \
    const int t_ = ((tt) < 32) ? (tt) : 31;                                              \
    char* const d_ = smem + (t_ & 1) * 32768 + 16384 + w * 1024;                         \
    glds16(Bbase + (size_t)t_ * 64, d_);                                                 \
    glds16(Bbase + (64 * 2048) + (size_t)t_ * 64, d_ + 8192);                            \
  }
#define T_RD_AHI(c)                                                                      \
  _Pragma("unroll") for (int mi = 2; mi < 4; ++mi)                                       \
  _Pragma("unroll") for (int kk = 0; kk < 2; ++kk)                                       \
      af[mi][kk] = *(const short8*)(smem + (c) * 32768 + ((wm * 4 + mi) * 2 + kk) * 1024 + fragOff);
#define T_RD_ALO(c)                                                                      \
  _Pragma("unroll") for (int mi = 0; mi < 2; ++mi)                                       \
  _Pragma("unroll") for (int kk = 0; kk < 2; ++kk)                                       \
      af[mi][kk] = *(const short8*)(smem + (c) * 32768 + ((wm * 4 + mi) * 2 + kk) * 1024 + fragOff);
#define T_RD_B(c)                                                                        \
  _Pragma("unroll") for (int ni = 0; ni < 2; ++ni)                                       \
  _Pragma("unroll") for (int kk = 0; kk < 2; ++kk)                                       \
      bf[ni][kk] = *(const short8*)(smem + (c) * 32768 + 16384 + (cb[ni] * 2 + kk) * 1024 + fragOff);

  f32x4 acc[4][2];
  const f32x4 fz = {0.f, 0.f, 0.f, 0.f};
#pragma unroll
  for (int i = 0; i < 4; ++i) { acc[i][0] = fz; acc[i][1] = fz; }

  short8 af[4][2], bf[2][2];

#define T_MFMA(MI0)                                                              \
  _Pragma("unroll") for (int kk = 0; kk < 2; ++kk)                               \
  _Pragma("unroll") for (int mi = 0; mi < 2; ++mi)                               \
  _Pragma("unroll") for (int ni = 0; ni < 2; ++ni)                               \
      acc[(MI0) + mi][ni] = __builtin_amdgcn_mfma_f32_16x16x32_bf16(             \
          af[(MI0) + mi][kk], bf[ni][kk], acc[(MI0) + mi][ni], 0, 0, 0);

  // prologue: A(0), B(0), A(1); gate -> barrier (all waves' tile0 drained)
  T_STAGE_A(0) T_STAGE_B(0) T_STAGE_A(1)
  asm volatile("s_waitcnt vmcnt(2)" ::: "memory");
  BARF()

#define T_TILE(c, tt)                                                                \
  /* P1 */ T_RD_AHI(c)                                                               \
  asm volatile("" ::: "memory");                                                     \
  T_RD_ALO(c) T_RD_B(c)                                                              \
  T_STAGE_B((tt) + 1)                                                                \
  BARF()                                                                             \
  __builtin_amdgcn_s_setprio(1); T_MFMA(0) __builtin_amdgcn_s_setprio(0);            \
  BARF()                                                                             \
  /* P2 */ T_STAGE_A((tt) + 2)                                                       \
  BARF()                                                                             \
  __builtin_amdgcn_s_setprio(1); T_MFMA(2) __builtin_amdgcn_s_setprio(0);            \
  asm volatile("s_waitcnt vmcnt(2)" ::: "memory");                                   \
  BARF()

#pragma unroll 1
  for (int T = 0; T < 32; T += 2) {
    T_TILE(0, T)
    T_TILE(1, T + 1)
  }
  asm volatile("s_waitcnt vmcnt(0)" ::: "memory");   // drain clamped tail rewrites
#undef T_TILE
#undef T_MFMA
#undef T_RD_AHI
#undef T_RD_ALO
#undef T_RD_B
#undef T_STAGE_A
#undef T_STAGE_B

  // ------------------------------------------------------------------ epilogues
  const int tb0 = m0 + wm * 64;
  if (mode == 0) {
#pragma unroll
    for (int mi = 0; mi < 4; ++mi) {
      const int row = tb0 + mi * 16 + quad * 4;
#pragma unroll
      for (int ni = 0; ni < 2; ++ni) {
        const int col = n0 + cb[ni] * 16 + l15;
#pragma unroll
        for (int r = 0; r < 4; ++r)
          Cout[(size_t)(row + r) * 2048 + col] = acc[mi][ni][r];
      }
    }
    return;
  }
  if (y >= 20) {
    // ---- V: store transposed into vtg[g][d][t]
    const int g = y - 20;
#pragma unroll
    for (int mi = 0; mi < 4; ++mi) {
      const int tb = tb0 + mi * 16 + quad * 4;
#pragma unroll
      for (int ni = 0; ni < 2; ++ni) {
        const int d = cb[ni] * 16 + l15;                // wn*16 + l15 + 64*ni
        u16x4 o;
#pragma unroll
        for (int r = 0; r < 4; ++r) o[r] = f2b(acc[mi][ni][r]);
        *(u16x4*)(vtg + (size_t)(g * 128 + d) * 4096 + tb) = o;
      }
    }
  } else {
    // ---- Q/K: thread-local RoPE; acc[mi][0] = dim i, acc[mi][1] = dim i+64
    unsigned short* dst;
    int stride, hoff;
    if (y < 16) { dst = qb; stride = 2048; hoff = y * 128; }
    else        { dst = kb; stride = 512;  hoff = (y - 16) * 128; }
    const float c2 = 0.20762050593045889f;   // log2(10000)/64
    const float inv2pi = 0.15915494309189535f;
    const int i = wn * 16 + l15;                        // rope dim, < 64
    const float inv_rev = exp2f(-(float)i * c2) * inv2pi;
#pragma unroll
    for (int mi = 0; mi < 4; ++mi) {
#pragma unroll
      for (int r = 0; r < 4; ++r) {
        const int t = tb0 + mi * 16 + quad * 4 + r;
        float rev = (float)t * inv_rev;
        rev -= floorf(rev);                    // [0,1) for HW v_sin/v_cos
        const float sn = __builtin_amdgcn_sinf(rev);
        const float cs = __builtin_amdgcn_cosf(rev);
        const float x1 = acc[mi][0][r], x2 = acc[mi][1][r];
        unsigned short* p = dst + (size_t)t * stride + hoff + i;
        p[0]  = f2b(x1 * cs - x2 * sn);
        p[64] = f2b(x1 * sn + x2 * cs);
      }
    }
  }
}

// ------------------------------------------------------------ windowed GQA attention
// CO-RESIDENT refactor of the 8-wave kernel: each old block was two independent
// 4-wave halves (wave w>>2 = query half) — split them into separate blocks.
// Block: 4 waves, 32 queries, one kv group; wave w = head g*4+w. Grid (128,4) =
// 512 blocks = 2 blocks/CU (32 KiB LDS, 256 thr) -> cross-block overlap of the
// per-chunk __syncthreads stalls. Per-query arithmetic identical to before.
// Every chunk in [s_begin, t0+31] is relevant to all waves -> no relevance branch.
// Each wave stages its K slab (2 glds) AND its V quarter (2 glds) per chunk.
__global__ __launch_bounds__(256) void attn_fwd(const unsigned short* __restrict__ qp,
                                                const unsigned short* __restrict__ kp,
                                                const unsigned short* __restrict__ vtg,
                                                unsigned short* __restrict__ op) {
  __shared__ unsigned short Ks[2][4][1024];   // [buf][kb][key*32+d']
  __shared__ unsigned short Vt[2][4096];      // [buf][d*32+key]
  const int tid = threadIdx.x;
  const int w = tid >> 6, lane = tid & 63;    // w in [0,4)
  const int quad = lane >> 4, l15 = lane & 15;
  const int t0 = blockIdx.x * 32;             // this block's 32-query base
  const int g = blockIdx.y;
  const int h = g * 4 + w;
  const f32x4 fzero = {0.f, 0.f, 0.f, 0.f};
  const float scale = 0.088388347648318447f;  // 1/sqrt(128)
  const float NEG_INF = -__builtin_inff();

  short8 qf[4][2];
#pragma unroll
  for (int qt = 0; qt < 2; qt++) {
    const unsigned short* qrow = qp + (size_t)(t0 + qt * 16 + l15) * 2048 + h * 128 + quad * 8;
#pragma unroll
    for (int kb = 0; kb < 4; kb++) qf[kb][qt] = *(const short8*)(qrow + kb * 32);
  }

  f32x4 oacc[8][2];
#pragma unroll
  for (int db = 0; db < 8; db++) { oacc[db][0] = fzero; oacc[db][1] = fzero; }
  float Mrow[2] = {-1.0e30f, -1.0e30f}, Lrow[2] = {0.f, 0.f};

  const int s_begin = (t0 >= 512) ? (t0 - 512) : 0;
  const int nch = ((t0 + 31 - s_begin) >> 5) + 1;

  const int r4 = lane >> 2, c4 = lane & 3;
  // wave w stages K slab w (dims [w*32, w*32+32)) and V quarter w (dims same range)
#define ATTN_STAGE(s0_, b_)                                                              \
  {                                                                                      \
    const int s0v = (s0_);                                                               \
    _Pragma("unroll")                                                                    \
    for (int p = 0; p < 2; p++)                                                          \
      glds16(kp + (size_t)(s0v + p * 16 + r4) * 512 + g * 128 + w * 32 + c4 * 8,         \
             &Ks[b_][w][p * 512]);                                                       \
    _Pragma("unroll")                                                                    \
    for (int p = 0; p < 2; p++)                                                          \
      glds16(vtg + (size_t)(g * 128 + w * 32 + p * 16 + r4) * 4096 + s0v + c4 * 8,       \
             &Vt[b_][w * 1024 + p * 512]);                                               \
  }

  ATTN_STAGE(s_begin, 0);

  for (int c = 0; c < nch; ++c) {
    const int s0 = s_begin + c * 32;
    const int b = c & 1;
    __syncthreads();                       // drain glds for chunk c (uniform)
    if (c + 1 < nch) ATTN_STAGE(s_begin + (c + 1) * 32, (c + 1) & 1);

    {
      // ---- S^T = K * Q^T, permuted key rows
      f32x4 sacc[2][2];
      sacc[0][0] = fzero; sacc[0][1] = fzero; sacc[1][0] = fzero; sacc[1][1] = fzero;
      const int permBase = ((l15 >> 2) << 3) + (l15 & 3);   // + 4*kt
#pragma unroll
      for (int kb = 0; kb < 4; kb++) {
        short8 af0 = *(const short8*)&Ks[b][kb][(permBase + 0) * 32 + quad * 8];
        short8 af1 = *(const short8*)&Ks[b][kb][(permBase + 4) * 32 + quad * 8];
        sacc[0][0] = __builtin_amdgcn_mfma_f32_16x16x32_bf16(af0, qf[kb][0], sacc[0][0], 0, 0, 0);
        sacc[0][1] = __builtin_amdgcn_mfma_f32_16x16x32_bf16(af0, qf[kb][1], sacc[0][1], 0, 0, 0);
        sacc[1][0] = __builtin_amdgcn_mfma_f32_16x16x32_bf16(af1, qf[kb][0], sacc[1][0], 0, 0, 0);
        sacc[1][1] = __builtin_amdgcn_mfma_f32_16x16x32_bf16(af1, qf[kb][1], sacc[1][1], 0, 0, 0);
      }

      // ---- masked online softmax; key for (kt,r) = s0 + quad*8 + kt*4 + r
      short8 pb[2];
      float alpha[2];
#pragma unroll
      for (int qt = 0; qt < 2; qt++) {
        const int tq = t0 + qt * 16 + l15;
        float vals[8];
        float cmax = NEG_INF;
#pragma unroll
        for (int kt = 0; kt < 2; kt++)
#pragma unroll
          for (int r = 0; r < 4; r++) {
            const int s = s0 + quad * 8 + kt * 4 + r;
            const bool ok = (unsigned)(tq - s) <= 512u;
            const float v = ok ? sacc[kt][qt][r] * scale : NEG_INF;
            vals[kt * 4 + r] = v;
            cmax = fmaxf(cmax, v);
          }
        cmax = fmaxf(cmax, __shfl_xor(cmax, 16));
        cmax = fmaxf(cmax, __shfl_xor(cmax, 32));
        const float Mnew = fmaxf(Mrow[qt], cmax);
        alpha[qt] = __expf(Mrow[qt] - Mnew);
        Mrow[qt] = Mnew;
        float csum = 0.f;
#pragma unroll
        for (int j = 0; j < 8; j++) {
          const float p = __expf(vals[j] - Mnew);   // exp(-inf) = 0 for masked
          csum += p;
          pb[qt][j] = (short)f2b(p);
        }
        csum += __shfl_xor(csum, 16);
        csum += __shfl_xor(csum, 32);
        Lrow[qt] = Lrow[qt] * alpha[qt] + csum;
      }

      // ---- O^T += V^T * P^T
#pragma unroll
      for (int db = 0; db < 8; db++) {
        short8 vf = *(const short8*)&Vt[b][(db * 16 + l15) * 32 + quad * 8];
#pragma unroll
        for (int qt = 0; qt < 2; qt++) {
          oacc[db][qt][0] *= alpha[qt]; oacc[db][qt][1] *= alpha[qt];
          oacc[db][qt][2] *= alpha[qt]; oacc[db][qt][3] *= alpha[qt];
          oacc[db][qt] = __builtin_amdgcn_mfma_f32_16x16x32_bf16(vf, pb[qt], oacc[db][qt], 0, 0, 0);
        }
      }
    }
  }
#undef ATTN_STAGE

#pragma unroll
  for (int qt = 0; qt < 2; qt++) {
    const float invL = 1.f / Lrow[qt];
    unsigned short* orow = op + (size_t)(t0 + qt * 16 + l15) * 2048 + h * 128;
#pragma unroll
    for (int db = 0; db < 8; db++) {
      u16x4 o;
#pragma unroll
      for (int r = 0; r < 4; r++) o[r] = f2b(oacc[db][qt][r] * invL);
      *(u16x4*)(orow + db * 16 + quad * 4) = o;
    }
  }
}

// ---------------------------------------------------------------- launch
extern "C" void kernel_launch(void* const* d_in, const int* in_sizes, int n_in,
                              void* d_out, int out_size, void* d_ws, size_t ws_size,
                              hipStream_t stream) {
  const float* x  = (const float*)d_in[0];
  const float* wq = (const float*)d_in[1];
  const float* wk = (const float*)d_in[2];
  const float* wv = (const float*)d_in[3];
  const float* wo = (const float*)d_in[4];
  float* out = (float*)d_out;
  char* ws = (char*)d_ws;

  // workspace map (~63 MB); attnb aliases xb (dead after qkv GEMM)
  unsigned short* xb    = (unsigned short*)(ws + 0);           // 16,777,216 B
  unsigned short* wqkv  = (unsigned short*)(ws + 16777216);    // 12,582,912 B
  unsigned short* wob   = (unsigned short*)(ws + 29360128);    //  8,388,608 B
  unsigned short* qb    = (unsigned short*)(ws + 37748736);    // 16,777,216 B
  unsigned short* kbuf  = (unsigned short*)(ws + 54525952);    //  4,194,304 B
  unsigned short* vtg   = (unsigned short*)(ws + 58720256);    //  4,194,304 B
  unsigned short* attnb = xb;

  static bool attr_done = false;
  if (!attr_done) {   // allow 64 KiB dynamic LDS (host-side, not stream-ordered)
    hipFuncSetAttribute(reinterpret_cast<const void*>(gemm_t128),
                        hipFuncAttributeMaxDynamicSharedMemorySize, 65536);
    attr_done = true;
  }

  cast_all<<<18432, 256, 0, stream>>>(x, wq, wk, wv, wo, (unsigned short*)ws);

  // qkv proj + fused RoPE + fused V-transpose: 128^2 tiles, 768 blocks, 2-resident
  gemm_t128<<<dim3(32, 24), 512, 65536, stream>>>(xb, wqkv, 1, qb, kbuf, vtg, nullptr);

  // attention: 32-query 4-wave blocks, 512 blocks, 2-resident
  attn_fwd<<<dim3(128, 4), 256, 0, stream>>>(qb, kbuf, vtg, attnb);

  // out = attn @ wo^T (4096 x 2048, K=2048) fp32 — gemm_t128 mode 0, 512 blocks
  gemm_t128<<<dim3(32, 16), 512, 65536, stream>>>(attnb, wob, 0,
                                                  nullptr, nullptr, nullptr, out);
}

// Round 10
// 239.924 us; speedup vs baseline: 1.0643x; 1.0643x over previous
//
#include <hip/hip_runtime.h>

typedef __attribute__((ext_vector_type(8))) short short8;
typedef __attribute__((ext_vector_type(4))) float f32x4;
typedef __attribute__((ext_vector_type(4))) unsigned short u16x4;

__device__ __forceinline__ unsigned short f2b(float f) {
  unsigned int u = __float_as_uint(f);
  u += 0x7fffu + ((u >> 16) & 1u);   // RNE
  return (unsigned short)(u >> 16);
}
__device__ __forceinline__ void glds16(const void* g, void* l) {
  __builtin_amdgcn_global_load_lds(
      (const __attribute__((address_space(1))) unsigned int*)g,
      (__attribute__((address_space(3))) unsigned int*)l, 16, 0, 0);
}

// ------------------------------------------------- fused cast: all 5 inputs -> bf16
__global__ __launch_bounds__(256) void cast_all(const float* __restrict__ x,
                                                const float* __restrict__ wq,
                                                const float* __restrict__ wk,
                                                const float* __restrict__ wv,
                                                const float* __restrict__ wo,
                                                unsigned short* __restrict__ dst) {
  const int i = blockIdx.x * 256 + threadIdx.x;   // < 4,718,592 (grid exact)
  const float* s;
  int off;
  if (i < 2097152)      { s = x;  off = i; }
  else if (i < 3145728) { s = wq; off = i - 2097152; }
  else if (i < 3407872) { s = wk; off = i - 3145728; }
  else if (i < 3670016) { s = wv; off = i - 3407872; }
  else                  { s = wo; off = i - 3670016; }
  f32x4 v = ((const f32x4*)s)[off];
  u16x4 o;
  o[0] = f2b(v[0]); o[1] = f2b(v[1]); o[2] = f2b(v[2]); o[3] = f2b(v[3]);
  ((u16x4*)dst)[i] = o;
}

#define BARF()                            \
  asm volatile("" ::: "memory");          \
  __builtin_amdgcn_s_barrier();           \
  asm volatile("" ::: "memory");

// ------------------------------------------------------------------ 128x128 2-phase GEMM
// qkv projection, CO-RESIDENT (R7-measured: 56.2 µs, VGPR 56, MfmaUtil 38%).
// BM=BN=128, BK=64 (K=2048, 32 tiles), 8 waves, 64 KiB LDS -> 2 blocks/CU.
// Grid (32,24) = 768 blocks. See R7 comments for schedule/soundness proofs.
__global__ __launch_bounds__(512, 4) void gemm_t128(
    const unsigned short* __restrict__ A, const unsigned short* __restrict__ B,
    const int mode,
    unsigned short* __restrict__ qb, unsigned short* __restrict__ kb,
    unsigned short* __restrict__ vtg, float* __restrict__ Cout) {
  extern __shared__ char smem[];   // 2 dbuf x [A 16K | B 16K] = 65536 B
  const int tid = threadIdx.x;
  const int w = tid >> 6, lane = tid & 63;
  const int quad = lane >> 4, l15 = lane & 15;
  const int wm = w >> 2, wn = w & 3;
  const int m0 = blockIdx.x * 128;
  const int y  = blockIdx.y;
  const int n0 = y * 128;

  int cb[2];
  cb[0] = mode ? wn : wn * 2;
  cb[1] = mode ? wn + 4 : wn * 2 + 1;

  const int fragOff = l15 * 64 + ((quad * 16) ^ ((l15 & 8) << 2));
  const int sr = lane >> 2;
  const int sc = ((lane & 3) * 8) ^ ((lane & 32) ? 16 : 0);   // bf16 col, pre-swizzled
  const unsigned short* const Abase = A + (size_t)(m0 + (w >> 1) * 16 + sr) * 2048 + (w & 1) * 32 + sc;
  const unsigned short* const Bbase = B + (size_t)(n0 + (w >> 1) * 16 + sr) * 2048 + (w & 1) * 32 + sc;

#define T_STAGE_A(tt)                                                                    \
  {                                                                                      \
    const int t_ = ((tt) < 32) ? (tt) : 31;                                              \
    char* const d_ = smem + (t_ & 1) * 32768 + w * 1024;                                 \
    glds16(Abase + (size_t)t_ * 64, d_);                                                 \
    glds16(Abase + (64 * 2048) + (size_t)t_ * 64, d_ + 8192);                            \
  }
#define T_STAGE_B(tt)                                                                    \
  {                                                                                      \
    const int t_ = ((tt) < 32) ? (tt) : 31;                                              \
    char* const d_ = smem + (t_ & 1) * 32768 + 16384 + w * 1024;                         \
    glds16(Bbase + (size_t)t_ * 64, d_);                                                 \
    glds16(Bbase + (64 * 2048) + (size_t)t_ * 64, d_ + 8192);                            \
  }
#define T_RD_AHI(c)                                                                      \
  _Pragma("unroll") for (int mi = 2; mi < 4; ++mi)                                       \
  _Pragma("unroll") for (int kk = 0; kk < 2; ++kk)                                       \
      af[mi][kk] = *(const short8*)(smem + (c) * 32768 + ((wm * 4 + mi) * 2 + kk) * 1024 + fragOff);
#define T_RD_ALO(c)                                                                      \
  _Pragma("unroll") for (int mi = 0; mi < 2; ++mi)                                       \
  _Pragma("unroll") for (int kk = 0; kk < 2; ++kk)                                       \
      af[mi][kk] = *(const short8*)(smem + (c) * 32768 + ((wm * 4 + mi) * 2 + kk) * 1024 + fragOff);
#define T_RD_B(c)                                                                        \
  _Pragma("unroll") for (int ni = 0; ni < 2; ++ni)                                       \
  _Pragma("unroll") for (int kk = 0; kk < 2; ++kk)                                       \
      bf[ni][kk] = *(const short8*)(smem + (c) * 32768 + 16384 + (cb[ni] * 2 + kk) * 1024 + fragOff);

  f32x4 acc[4][2];
  const f32x4 fz = {0.f, 0.f, 0.f, 0.f};
#pragma unroll
  for (int i = 0; i < 4; ++i) { acc[i][0] = fz; acc[i][1] = fz; }

  short8 af[4][2], bf[2][2];

#define T_MFMA(MI0)                                                              \
  _Pragma("unroll") for (int kk = 0; kk < 2; ++kk)                               \
  _Pragma("unroll") for (int mi = 0; mi < 2; ++mi)                               \
  _Pragma("unroll") for (int ni = 0; ni < 2; ++ni)                               \
      acc[(MI0) + mi][ni] = __builtin_amdgcn_mfma_f32_16x16x32_bf16(             \
          af[(MI0) + mi][kk], bf[ni][kk], acc[(MI0) + mi][ni], 0, 0, 0);

  // prologue: A(0), B(0), A(1); gate -> barrier (all waves' tile0 drained)
  T_STAGE_A(0) T_STAGE_B(0) T_STAGE_A(1)
  asm volatile("s_waitcnt vmcnt(2)" ::: "memory");
  BARF()

#define T_TILE(c, tt)                                                                \
  /* P1 */ T_RD_AHI(c)                                                               \
  asm volatile("" ::: "memory");                                                     \
  T_RD_ALO(c) T_RD_B(c)                                                              \
  T_STAGE_B((tt) + 1)                                                                \
  BARF()                                                                             \
  __builtin_amdgcn_s_setprio(1); T_MFMA(0) __builtin_amdgcn_s_setprio(0);            \
  BARF()                                                                             \
  /* P2 */ T_STAGE_A((tt) + 2)                                                       \
  BARF()                                                                             \
  __builtin_amdgcn_s_setprio(1); T_MFMA(2) __builtin_amdgcn_s_setprio(0);            \
  asm volatile("s_waitcnt vmcnt(2)" ::: "memory");                                   \
  BARF()

#pragma unroll 1
  for (int T = 0; T < 32; T += 2) {
    T_TILE(0, T)
    T_TILE(1, T + 1)
  }
  asm volatile("s_waitcnt vmcnt(0)" ::: "memory");   // drain clamped tail rewrites
#undef T_TILE
#undef T_MFMA
#undef T_RD_AHI
#undef T_RD_ALO
#undef T_RD_B
#undef T_STAGE_A
#undef T_STAGE_B

  // ------------------------------------------------------------------ epilogues
  const int tb0 = m0 + wm * 64;
  if (mode == 0) {
#pragma unroll
    for (int mi = 0; mi < 4; ++mi) {
      const int row = tb0 + mi * 16 + quad * 4;
#pragma unroll
      for (int ni = 0; ni < 2; ++ni) {
        const int col = n0 + cb[ni] * 16 + l15;
#pragma unroll
        for (int r = 0; r < 4; ++r)
          Cout[(size_t)(row + r) * 2048 + col] = acc[mi][ni][r];
      }
    }
    return;
  }
  if (y >= 20) {
    // ---- V: store transposed into vtg[g][d][t]
    const int g = y - 20;
#pragma unroll
    for (int mi = 0; mi < 4; ++mi) {
      const int tb = tb0 + mi * 16 + quad * 4;
#pragma unroll
      for (int ni = 0; ni < 2; ++ni) {
        const int d = cb[ni] * 16 + l15;                // wn*16 + l15 + 64*ni
        u16x4 o;
#pragma unroll
        for (int r = 0; r < 4; ++r) o[r] = f2b(acc[mi][ni][r]);
        *(u16x4*)(vtg + (size_t)(g * 128 + d) * 4096 + tb) = o;
      }
    }
  } else {
    // ---- Q/K: thread-local RoPE; acc[mi][0] = dim i, acc[mi][1] = dim i+64
    unsigned short* dst;
    int stride, hoff;
    if (y < 16) { dst = qb; stride = 2048; hoff = y * 128; }
    else        { dst = kb; stride = 512;  hoff = (y - 16) * 128; }
    const float c2 = 0.20762050593045889f;   // log2(10000)/64
    const float inv2pi = 0.15915494309189535f;
    const int i = wn * 16 + l15;                        // rope dim, < 64
    const float inv_rev = exp2f(-(float)i * c2) * inv2pi;
#pragma unroll
    for (int mi = 0; mi < 4; ++mi) {
#pragma unroll
      for (int r = 0; r < 4; ++r) {
        const int t = tb0 + mi * 16 + quad * 4 + r;
        float rev = (float)t * inv_rev;
        rev -= floorf(rev);                    // [0,1) for HW v_sin/v_cos
        const float sn = __builtin_amdgcn_sinf(rev);
        const float cs = __builtin_amdgcn_cosf(rev);
        const float x1 = acc[mi][0][r], x2 = acc[mi][1][r];
        unsigned short* p = dst + (size_t)t * stride + hoff + i;
        p[0]  = f2b(x1 * cs - x2 * sn);
        p[64] = f2b(x1 * sn + x2 * cs);
      }
    }
  }
}

// ------------------------------------------------------------------ 128x256 2-phase GEMM
// C = A * B^T fp32 (wo projection). Grid (32,8) = 256 blocks. R6-hardened schedule
// (vmcnt(2) gate before P2's closing barrier, cross-wave sound).
__global__ __launch_bounds__(512, 2) void gemm128(const unsigned short* __restrict__ A,
                                                  const unsigned short* __restrict__ B,
                                                  float* __restrict__ Cout) {
  extern __shared__ char smem[];   // 2 x 49152 B
  const int tid = threadIdx.x;
  const int w = tid >> 6, lane = tid & 63;
  const int quad = lane >> 4, l15 = lane & 15;
  const int wm = w >> 2, wn = w & 3;
  const int m0 = blockIdx.x * 128, n0 = blockIdx.y * 256;

  const int fragOff = l15 * 64 + ((quad * 16) ^ ((l15 & 8) << 2));
  char* const aWave = smem;                              // + dbuf*49152
  char* const bWave = smem + 16384 + (wn >> 1) * 16384;

  const int sr = lane >> 2;
  const int sc = ((lane & 3) * 8) ^ ((lane & 32) ? 16 : 0);   // bf16 col, pre-swizzled
  const unsigned short* const Abase = A + (size_t)(m0 + (w >> 1) * 16 + sr) * 2048 + (w & 1) * 32 + sc;
  const unsigned short* const Bbase = B + (size_t)(n0 + (w >> 1) * 16 + sr) * 2048 + (w & 1) * 32 + sc;

#define G_STAGE_A(tt)                                                                    \
  {                                                                                      \
    const int t_ = ((tt) < 32) ? (tt) : 31;                                              \
    char* const d_ = smem + (t_ & 1) * 49152 + w * 1024;                                 \
    glds16(Abase + (size_t)t_ * 64, d_);                                                 \
    glds16(Abase + (64 * 2048) + (size_t)t_ * 64, d_ + 8192);                            \
  }
#define G_STAGE_B(h, tt)                                                                 \
  {                                                                                      \
    const int t_ = ((tt) < 32) ? (tt) : 31;                                              \
    char* const d_ = smem + (t_ & 1) * 49152 + 16384 + (h) * 16384 + w * 1024;           \
    glds16(Bbase + (size_t)(h) * (128 * 2048) + (size_t)t_ * 64, d_);                    \
    glds16(Bbase + (size_t)(h) * (128 * 2048) + (64 * 2048) + (size_t)t_ * 64, d_ + 8192); \
  }
#define G_RD_A(c)                                                                        \
  _Pragma("unroll") for (int mi = 0; mi < 4; ++mi)                                       \
  _Pragma("unroll") for (int kk = 0; kk < 2; ++kk)                                       \
      af[mi][kk] = *(const short8*)(aWave + (c) * 49152 + ((wm * 4 + mi) * 2 + kk) * 1024 + fragOff);
#define G_RD_B(dst, c, NI0)                                                              \
  _Pragma("unroll") for (int ni = 0; ni < 2; ++ni)                                       \
  _Pragma("unroll") for (int kk = 0; kk < 2; ++kk)                                       \
      dst[ni][kk] = *(const short8*)(bWave + (c) * 49152 + (((wn & 1) * 4 + (NI0) + ni) * 2 + kk) * 1024 + fragOff);

  f32x4 acc[4][4];
  const f32x4 fz = {0.f, 0.f, 0.f, 0.f};
#pragma unroll
  for (int i = 0; i < 4; ++i)
#pragma unroll
    for (int j = 0; j < 4; ++j) acc[i][j] = fz;

  short8 af[4][2], blo[2][2], bhi[2][2];

#define G_MFMA(NOFF, BF)                                                         \
  _Pragma("unroll") for (int kk = 0; kk < 2; ++kk)                               \
  _Pragma("unroll") for (int mi = 0; mi < 4; ++mi)                               \
  _Pragma("unroll") for (int ni = 0; ni < 2; ++ni)                               \
      acc[mi][(NOFF) + ni] = __builtin_amdgcn_mfma_f32_16x16x32_bf16(            \
          af[mi][kk], BF[ni][kk], acc[mi][(NOFF) + ni], 0, 0, 0);

  // prologue: A(0)x2, B(0)x4, A(1)x2; gate -> barrier
  G_STAGE_A(0) G_STAGE_B(0, 0) G_STAGE_B(1, 0) G_STAGE_A(1)
  asm volatile("s_waitcnt vmcnt(2)" ::: "memory");
  BARF()

#define G_TILE(c, tt)                                                                \
  /* P1 */ G_RD_A(c) G_RD_B(blo, (c), 0)                                             \
  G_STAGE_B(0, (tt) + 1) G_STAGE_B(1, (tt) + 1)                                      \
  BARF()                                                                             \
  __builtin_amdgcn_s_setprio(1); G_MFMA(0, blo) __builtin_amdgcn_s_setprio(0);       \
  BARF()                                                                             \
  /* P2 */ G_RD_B(bhi, (c), 2)                                                       \
  G_STAGE_A((tt) + 2)                                                                \
  BARF()                                                                             \
  __builtin_amdgcn_s_setprio(1); G_MFMA(2, bhi) __builtin_amdgcn_s_setprio(0);       \
  asm volatile("s_waitcnt vmcnt(2)" ::: "memory");                                   \
  BARF()

#pragma unroll 1
  for (int T = 0; T < 32; T += 2) {
    G_TILE(0, T)
    G_TILE(1, T + 1)
  }
  asm volatile("s_waitcnt vmcnt(0)" ::: "memory");   // drain clamped tail rewrites
#undef G_TILE
#undef G_MFMA
#undef G_RD_A
#undef G_RD_B
#undef G_STAGE_A
#undef G_STAGE_B

  const int colBase = n0 + wn * 64;
#pragma unroll
  for (int mi = 0; mi < 4; ++mi) {
    const int row = m0 + wm * 64 + mi * 16 + quad * 4;
#pragma unroll
    for (int ni = 0; ni < 4; ++ni) {
      const int col = colBase + ni * 16 + l15;
#pragma unroll
      for (int r = 0; r < 4; ++r)
        Cout[(size_t)(row + r) * 2048 + col] = acc[mi][ni][r];
    }
  }
}

// ------------------------------------------------------------ windowed GQA attention
// R7 structure (8 waves, 64 queries, grid (64,4)) + LDS XOR de-conflict (this round):
// K element (key k, dim-group c) stored at c ^ hK(k), hK(k)=((k>>1)^(k>>3))&3;
// V element (dim d, key-group c) stored at c ^ hV(d), hV(d)=(d>>1)&3.
// Both applied as pre-swizzled GLOBAL source (glds dest linear, rule 21) + matching
// XOR on the fragment reads. Enumeration check: QK^T K-read and PV V-read conflict
// sets drop 8-way -> 2-way (free, m136). Values/MFMA order unchanged -> bit-identical.
__global__ __launch_bounds__(512) void attn_fwd(const unsigned short* __restrict__ qp,
                                                const unsigned short* __restrict__ kp,
                                                const unsigned short* __restrict__ vtg,
                                                unsigned short* __restrict__ op) {
  __shared__ unsigned short Ks[2][4][1024];   // [buf][kb][key*32 + swz dim]
  __shared__ unsigned short Vt[2][4096];      // [buf][d*32 + swz key]
  const int tid = threadIdx.x;
  const int w = tid >> 6, lane = tid & 63;
  const int quad = lane >> 4, l15 = lane & 15;
  const int t0 = blockIdx.x * 64;
  const int g = blockIdx.y;
  const int h = g * 4 + (w & 3);
  const int t0w = t0 + (w >> 2) * 32;         // this wave's 32-query base
  const f32x4 fzero = {0.f, 0.f, 0.f, 0.f};
  const float scale = 0.088388347648318447f;  // 1/sqrt(128)
  const float NEG_INF = -__builtin_inff();

  short8 qf[4][2];
#pragma unroll
  for (int qt = 0; qt < 2; qt++) {
    const unsigned short* qrow = qp + (size_t)(t0w + qt * 16 + l15) * 2048 + h * 128 + quad * 8;
#pragma unroll
    for (int kb = 0; kb < 4; kb++) qf[kb][qt] = *(const short8*)(qrow + kb * 32);
  }

  f32x4 oacc[8][2];
#pragma unroll
  for (int db = 0; db < 8; db++) { oacc[db][0] = fzero; oacc[db][1] = fzero; }
  float Mrow[2] = {-1.0e30f, -1.0e30f}, Lrow[2] = {0.f, 0.f};

  const int s_begin = (t0 >= 512) ? (t0 - 512) : 0;
  const int nch = ((t0 + 63 - s_begin) >> 5) + 1;

  const int r4 = lane >> 2, c4 = lane & 3;
  // wave w<4 stages K slab w; wave w>=4 stages V^T quarter (w-4). Pre-swizzled src:
  // K: dim-group c4 ^ hK(key), key = p*16+r4. V: key-group c4 ^ hV(d), d%16 = r4.
#define ATTN_STAGE(s0_, b_)                                                              \
  {                                                                                      \
    const int s0v = (s0_);                                                               \
    if (w < 4) {                                                                         \
      _Pragma("unroll")                                                                  \
      for (int p = 0; p < 2; p++) {                                                      \
        const int kkey = p * 16 + r4;                                                    \
        const int hk = ((kkey >> 1) ^ (kkey >> 3)) & 3;                                  \
        glds16(kp + (size_t)(s0v + kkey) * 512 + g * 128 + w * 32 + (c4 ^ hk) * 8,       \
               &Ks[b_][w][p * 512]);                                                     \
      }                                                                                  \
    } else {                                                                             \
      const int wv = w - 4;                                                              \
      const int hv = (r4 >> 1) & 3;                                                      \
      _Pragma("unroll")                                                                  \
      for (int p = 0; p < 2; p++)                                                        \
        glds16(vtg + (size_t)(g * 128 + wv * 32 + p * 16 + r4) * 4096 + s0v + (c4 ^ hv) * 8, \
               &Vt[b_][wv * 1024 + p * 512]);                                            \
    }                                                                                    \
  }

  ATTN_STAGE(s_begin, 0);

  for (int c = 0; c < nch; ++c) {
    const int s0 = s_begin + c * 32;
    const int b = c & 1;
    __syncthreads();                       // drain glds for chunk c (uniform)
    if (c + 1 < nch) ATTN_STAGE(s_begin + (c + 1) * 32, (c + 1) & 1);

    // wave-relevance: this wave's queries [t0w, t0w+31] vs keys [s0, s0+31]
    if (s0 + 31 >= t0w - 512 && s0 <= t0w + 31) {
      // ---- S^T = K * Q^T, permuted key rows (reads de-swizzled via hK)
      f32x4 sacc[2][2];
      sacc[0][0] = fzero; sacc[0][1] = fzero; sacc[1][0] = fzero; sacc[1][1] = fzero;
      const int permBase = ((l15 >> 2) << 3) + (l15 & 3);   // + 4*kt
      const int row0 = permBase, row1 = permBase + 4;
      const int co0 = ((quad ^ (((row0 >> 1) ^ (row0 >> 3)) & 3)) * 8);
      const int co1 = ((quad ^ (((row1 >> 1) ^ (row1 >> 3)) & 3)) * 8);
#pragma unroll
      for (int kb = 0; kb < 4; kb++) {
        short8 af0 = *(const short8*)&Ks[b][kb][row0 * 32 + co0];
        short8 af1 = *(const short8*)&Ks[b][kb][row1 * 32 + co1];
        sacc[0][0] = __builtin_amdgcn_mfma_f32_16x16x32_bf16(af0, qf[kb][0], sacc[0][0], 0, 0, 0);
        sacc[0][1] = __builtin_amdgcn_mfma_f32_16x16x32_bf16(af0, qf[kb][1], sacc[0][1], 0, 0, 0);
        sacc[1][0] = __builtin_amdgcn_mfma_f32_16x16x32_bf16(af1, qf[kb][0], sacc[1][0], 0, 0, 0);
        sacc[1][1] = __builtin_amdgcn_mfma_f32_16x16x32_bf16(af1, qf[kb][1], sacc[1][1], 0, 0, 0);
      }

      // ---- masked online softmax; key for (kt,r) = s0 + quad*8 + kt*4 + r
      short8 pb[2];
      float alpha[2];
#pragma unroll
      for (int qt = 0; qt < 2; qt++) {
        const int tq = t0w + qt * 16 + l15;
        float vals[8];
        float cmax = NEG_INF;
#pragma unroll
        for (int kt = 0; kt < 2; kt++)
#pragma unroll
          for (int r = 0; r < 4; r++) {
            const int s = s0 + quad * 8 + kt * 4 + r;
            const bool ok = (unsigned)(tq - s) <= 512u;
            const float v = ok ? sacc[kt][qt][r] * scale : NEG_INF;
            vals[kt * 4 + r] = v;
            cmax = fmaxf(cmax, v);
          }
        cmax = fmaxf(cmax, __shfl_xor(cmax, 16));
        cmax = fmaxf(cmax, __shfl_xor(cmax, 32));
        const float Mnew = fmaxf(Mrow[qt], cmax);
        alpha[qt] = __expf(Mrow[qt] - Mnew);
        Mrow[qt] = Mnew;
        float csum = 0.f;
#pragma unroll
        for (int j = 0; j < 8; j++) {
          const float p = __expf(vals[j] - Mnew);   // exp(-inf) = 0 for masked
          csum += p;
          pb[qt][j] = (short)f2b(p);
        }
        csum += __shfl_xor(csum, 16);
        csum += __shfl_xor(csum, 32);
        Lrow[qt] = Lrow[qt] * alpha[qt] + csum;
      }

      // ---- O^T += V^T * P^T (V read de-swizzled via hV; hV(db*16+l15) = (l15>>1)&3)
      const int vco = (quad ^ ((l15 >> 1) & 3)) * 8;
#pragma unroll
      for (int db = 0; db < 8; db++) {
        short8 vf = *(const short8*)&Vt[b][(db * 16 + l15) * 32 + vco];
#pragma unroll
        for (int qt = 0; qt < 2; qt++) {
          oacc[db][qt][0] *= alpha[qt]; oacc[db][qt][1] *= alpha[qt];
          oacc[db][qt][2] *= alpha[qt]; oacc[db][qt][3] *= alpha[qt];
          oacc[db][qt] = __builtin_amdgcn_mfma_f32_16x16x32_bf16(vf, pb[qt], oacc[db][qt], 0, 0, 0);
        }
      }
    }
  }
#undef ATTN_STAGE

#pragma unroll
  for (int qt = 0; qt < 2; qt++) {
    const float invL = 1.f / Lrow[qt];
    unsigned short* orow = op + (size_t)(t0w + qt * 16 + l15) * 2048 + h * 128;
#pragma unroll
    for (int db = 0; db < 8; db++) {
      u16x4 o;
#pragma unroll
      for (int r = 0; r < 4; r++) o[r] = f2b(oacc[db][qt][r] * invL);
      *(u16x4*)(orow + db * 16 + quad * 4) = o;
    }
  }
}

// ---------------------------------------------------------------- launch
extern "C" void kernel_launch(void* const* d_in, const int* in_sizes, int n_in,
                              void* d_out, int out_size, void* d_ws, size_t ws_size,
                              hipStream_t stream) {
  const float* x  = (const float*)d_in[0];
  const float* wq = (const float*)d_in[1];
  const float* wk = (const float*)d_in[2];
  const float* wv = (const float*)d_in[3];
  const float* wo = (const float*)d_in[4];
  float* out = (float*)d_out;
  char* ws = (char*)d_ws;

  // workspace map (~63 MB); attnb aliases xb (dead after qkv GEMM)
  unsigned short* xb    = (unsigned short*)(ws + 0);           // 16,777,216 B
  unsigned short* wqkv  = (unsigned short*)(ws + 16777216);    // 12,582,912 B
  unsigned short* wob   = (unsigned short*)(ws + 29360128);    //  8,388,608 B
  unsigned short* qb    = (unsigned short*)(ws + 37748736);    // 16,777,216 B
  unsigned short* kbuf  = (unsigned short*)(ws + 54525952);    //  4,194,304 B
  unsigned short* vtg   = (unsigned short*)(ws + 58720256);    //  4,194,304 B
  unsigned short* attnb = xb;

  static bool attr_done = false;
  if (!attr_done) {   // allow big dynamic LDS (host-side, not stream-ordered)
    hipFuncSetAttribute(reinterpret_cast<const void*>(gemm_t128),
                        hipFuncAttributeMaxDynamicSharedMemorySize, 65536);
    hipFuncSetAttribute(reinterpret_cast<const void*>(gemm128),
                        hipFuncAttributeMaxDynamicSharedMemorySize, 98304);
    attr_done = true;
  }

  cast_all<<<18432, 256, 0, stream>>>(x, wq, wk, wv, wo, (unsigned short*)ws);

  // qkv proj + fused RoPE + fused V-transpose: 128^2 tiles, 768 blocks, 2-resident
  gemm_t128<<<dim3(32, 24), 512, 65536, stream>>>(xb, wqkv, 1, qb, kbuf, vtg, nullptr);

  // attention: R7 8-wave structure + K/V LDS de-conflict swizzle
  attn_fwd<<<dim3(64, 4), 512, 0, stream>>>(qb, kbuf, vtg, attnb);

  // out = attn @ wo^T  (4096 x 2048, K=2048), fp32 out — 128x256 tiles, 256 blocks
  gemm128<<<dim3(32, 8), 512, 98304, stream>>>(attnb, wob, out);
}